// Round 2
// baseline (387.550 us; speedup 1.0000x reference)
//
#include <hip/hip_runtime.h>

#define Bc 2
#define Sc 2048
#define Hc 2048
#define NHc 16
#define HDc 128
#define SLOTSc 16
#define NROWS (Bc * Sc)   // 4096

// ---------------------------------------------------------------------------
// Kernel 1: actions = softmax( (hidden @ W_action^T + b) / sqrt(128) )
// C is [4096 rows][16 heads][3]. Thread-per-head: each thread computes one
// head's 3 logits (dot-2048 each) and the 3-way softmax, fully in registers.
// Block = 256 threads = 16 rows x 16 heads. Grid = 256 blocks.
// W_action (384 KB) is L2-resident; 16-row blocks amortize W reads 16x.
// ---------------------------------------------------------------------------
__global__ __launch_bounds__(256) void actions_kernel(
    const float* __restrict__ hidden,    // [4096][2048]
    const float* __restrict__ W_action,  // [48][2048]
    const float* __restrict__ b_action,  // [48]
    float* __restrict__ actions)         // [4096][16][3]
{
    const int rl   = threadIdx.x >> 4;         // 0..15 local row
    const int head = threadIdx.x & 15;         // 0..15
    const int r    = blockIdx.x * 16 + rl;
    const int c0   = 3 * head;

    const float4* A  = (const float4*)(hidden + (size_t)r * Hc);
    const float4* B0 = (const float4*)(W_action + (size_t)c0 * Hc);
    const float4* B1 = B0 + (Hc / 4);
    const float4* B2 = B1 + (Hc / 4);

    float s0 = 0.f, s1 = 0.f, s2 = 0.f;
    #pragma unroll 8
    for (int k = 0; k < Hc / 4; ++k) {
        float4 a  = A[k];
        float4 b0 = B0[k];
        float4 b1 = B1[k];
        float4 b2 = B2[k];
        s0 = fmaf(a.x, b0.x, fmaf(a.y, b0.y, fmaf(a.z, b0.z, fmaf(a.w, b0.w, s0))));
        s1 = fmaf(a.x, b1.x, fmaf(a.y, b1.y, fmaf(a.z, b1.z, fmaf(a.w, b1.w, s1))));
        s2 = fmaf(a.x, b2.x, fmaf(a.y, b2.y, fmaf(a.z, b2.z, fmaf(a.w, b2.w, s2))));
    }
    const float scale = 0.08838834764831845f; // 1/sqrt(128)
    float l0 = (s0 + b_action[c0 + 0]) * scale;
    float l1 = (s1 + b_action[c0 + 1]) * scale;
    float l2 = (s2 + b_action[c0 + 2]) * scale;
    float lm = fmaxf(l0, fmaxf(l1, l2));
    float e0 = __expf(l0 - lm), e1 = __expf(l1 - lm), e2 = __expf(l2 - lm);
    float inv = 1.f / (e0 + e1 + e2);

    float* ap = actions + ((size_t)r * NHc + head) * 3;
    ap[0] = e0 * inv;
    ap[1] = e1 * inv;
    ap[2] = e2 * inv;
}

// ---------------------------------------------------------------------------
// Kernel 2: pure streaming. One INDEPENDENT wave per (b,s,head) stream —
// no __syncthreads, no LDS, 256-thread blocks (4 waves = 4 heads) so the CU
// scheduler mixes waves at different phases and the gate shuffles hide under
// the HBM stream. Lane l owns dims 2l,2l+1 (float2, 8B/lane coalesced).
// ---------------------------------------------------------------------------
__global__ __launch_bounds__(256, 4) void stack_stream(
    const float* __restrict__ hidden,     // [4096][2048]
    const float* __restrict__ stack,      // [4096][16][16][128]
    const float* __restrict__ mask,       // [4096][16][16]
    const float* __restrict__ actions,    // [4096][16][3]
    const float* __restrict__ W_gate,     // [128]
    const float* __restrict__ b_gate,     // [1]
    const float* __restrict__ res_weight, // [1]
    float* __restrict__ out,              // [4096][2048]
    float* __restrict__ new_stack,        // [4096][16][16][128]
    float* __restrict__ new_mask)         // [4096][16][16]
{
    const int bs   = blockIdx.x >> 2;
    const int hg   = blockIdx.x & 3;
    const int lane = threadIdx.x & 63;
    const int wave = threadIdx.x >> 6;
    const int n    = hg * 4 + wave;

    // ---- actions (wave-uniform broadcast loads) ----
    const float* ap = actions + ((size_t)bs * NHc + n) * 3;
    const float a_push = ap[0];
    const float a_pop  = ap[1];
    const float a_stay = ap[2];

    // ---- per-head pointers ----
    const size_t sbase = ((size_t)bs * NHc + n) * (size_t)(SLOTSc * HDc);
    const float2* st2  = (const float2*)(stack + sbase);
    float2*       nst2 = (float2*)(new_stack + sbase);

    float2 kv = *(const float2*)(hidden + (size_t)bs * Hc + n * HDc + 2 * lane);
    float2 wg = *(const float2*)(W_gate + 2 * lane);
    const float bg = b_gate[0];
    const float rw = res_weight[0];

    // ---- mask: 16 floats ----
    const float* mp = mask + ((size_t)bs * NHc + n) * SLOTSc;
    float m[SLOTSc];
    {
        float4 q0 = ((const float4*)mp)[0];
        float4 q1 = ((const float4*)mp)[1];
        float4 q2 = ((const float4*)mp)[2];
        float4 q3 = ((const float4*)mp)[3];
        m[0]=q0.x;  m[1]=q0.y;  m[2]=q0.z;  m[3]=q0.w;
        m[4]=q1.x;  m[5]=q1.y;  m[6]=q1.z;  m[7]=q1.w;
        m[8]=q2.x;  m[9]=q2.y;  m[10]=q2.z; m[11]=q2.w;
        m[12]=q3.x; m[13]=q3.y; m[14]=q3.z; m[15]=q3.w;
    }

    // ---- new_mask; write it ----
    float nm[SLOTSc];
    #pragma unroll
    for (int k = 0; k < SLOTSc; ++k) {
        float pm = (k == 0) ? 1.f : m[k - 1];
        float om = (k < SLOTSc - 1) ? m[k + 1] : 0.f;
        nm[k] = a_push * pm + a_pop * om + a_stay * m[k];
    }
    {
        float msel = nm[0];
        #pragma unroll
        for (int k = 1; k < SLOTSc; ++k) if (lane == k) msel = nm[k];
        if (lane < SLOTSc)
            new_mask[((size_t)bs * NHc + n) * SLOTSc + lane] = msel;
    }

    // ---- new_stack: rolling window, ns kept in regs ----
    float2 ns[SLOTSc];
    float2 prev = kv;
    float2 cur  = st2[lane];
    #pragma unroll
    for (int k = 0; k < SLOTSc; ++k) {
        float2 nxt;
        if (k < SLOTSc - 1) nxt = st2[(k + 1) * 64 + lane];
        else { nxt.x = 0.f; nxt.y = 0.f; }
        ns[k].x = a_push * prev.x + a_pop * nxt.x + a_stay * cur.x;
        ns[k].y = a_push * prev.y + a_pop * nxt.y + a_stay * cur.y;
        nst2[k * 64 + lane] = ns[k];
        prev = cur; cur = nxt;
    }

    // ---- gate scores: 16 x butterfly reductions (bias folded inline) ----
    float gs[SLOTSc];
    #pragma unroll
    for (int k = 0; k < SLOTSc; ++k) {
        float p = ns[k].x * wg.x + ns[k].y * wg.y;
        #pragma unroll
        for (int o = 32; o; o >>= 1) p += __shfl_xor(p, o, 64);
        gs[k] = p + bg + (1.f - nm[k]) * -1000000000.0f;
    }

    // ---- masked softmax over slots ----
    float mx = gs[0];
    #pragma unroll
    for (int k = 1; k < SLOTSc; ++k) mx = fmaxf(mx, gs[k]);
    float ssum = 0.f;
    #pragma unroll
    for (int k = 0; k < SLOTSc; ++k) { gs[k] = __expf(gs[k] - mx); ssum += gs[k]; }
    const float invs = 1.f / ssum;

    // ---- memory output + residual ----
    float2 mo; mo.x = 0.f; mo.y = 0.f;
    #pragma unroll
    for (int k = 0; k < SLOTSc; ++k) {
        float w = gs[k] * invs;
        mo.x = fmaf(w, ns[k].x, mo.x);
        mo.y = fmaf(w, ns[k].y, mo.y);
    }
    float2 ov;
    ov.x = mo.x * rw + kv.x;
    ov.y = mo.y * rw + kv.y;
    *(float2*)(out + (size_t)bs * Hc + n * HDc + 2 * lane) = ov;
}

extern "C" void kernel_launch(void* const* d_in, const int* in_sizes, int n_in,
                              void* d_out, int out_size, void* d_ws, size_t ws_size,
                              hipStream_t stream) {
    const float* hidden     = (const float*)d_in[0];
    const float* stack      = (const float*)d_in[1];
    const float* mask       = (const float*)d_in[2];
    const float* W_action   = (const float*)d_in[3];
    const float* b_action   = (const float*)d_in[4];
    const float* W_gate     = (const float*)d_in[5];
    const float* b_gate     = (const float*)d_in[6];
    const float* res_weight = (const float*)d_in[7];

    float* out       = (float*)d_out;
    float* new_stack = out + (size_t)Bc * Sc * Hc;
    float* new_mask  = new_stack + (size_t)Bc * Sc * NHc * SLOTSc * HDc;

    float* actions = (float*)d_ws; // 4096*16*3*4 = 786,432 B

    hipLaunchKernelGGL(actions_kernel, dim3(NROWS / 16), dim3(256), 0, stream,
                       hidden, W_action, b_action, actions);

    hipLaunchKernelGGL(stack_stream, dim3(NROWS * 4), dim3(256), 0, stream,
                       hidden, stack, mask, actions, W_gate, b_gate, res_weight,
                       out, new_stack, new_mask);
}